// Round 6
// baseline (696.868 us; speedup 1.0000x reference)
//
#include <hip/hip_runtime.h>
#include <math.h>

namespace {
constexpr int B = 4;
constexpr int S = 4096;
constexpr int H = 2048;
constexpr int DR = 3;          // depth
constexpr int KSEL = 1365;     // int(4096/3)
constexpr int SCORE_BLKS = 2048;          // 4 waves/block, 2 tokens/wave
constexpr int WAVES_PER_BATCH = 2048;     // 512 blocks * 4 waves
constexpr int NBLK = SCORE_BLKS + B + 1;  // + 4 select blocks + 1 loss block
constexpr unsigned FONE = 0x3F800000u;    // bits of 1.0f
typedef float fx4 __attribute__((ext_vector_type(4)));
}

// ---------------------------------------------------------------------------
// Fused kernel.
//  blocks [0,2048): scores. raw[d][t]=dot(hidden[t,:],w[d,:]); sc=sigmoid(raw)
//    (exp-form f32). Keys (bits of sc0) stored; per-wave release-signal to
//    cnt[batch]; per-block loss partials + release-signal to cnt[B].
//  blocks [2048,2052): per-batch exact top-KSEL (value desc, index asc) after
//    acquire-spin on cnt[batch]. Fast path when count(key==1.0f)>=KSEL.
//  block 2052: balancing-loss reduction after acquire-spin on cnt[B].
// Cross-XCD visibility: writer = store + __threadfence + release-atomic;
// reader = acquire-atomic spin (invalidates L1/L2) + __syncthreads.
// ---------------------------------------------------------------------------
__global__ __launch_bounds__(256, 4) void ecr_fused(const float* __restrict__ hid,
                                                    const float* __restrict__ w,
                                                    unsigned* __restrict__ keys,
                                                    float* __restrict__ partials,
                                                    unsigned* __restrict__ cnt,
                                                    float* __restrict__ out) {
    const int blk = blockIdx.x;
    const int t = threadIdx.x;
    const int wave = t >> 6;
    const int lane = t & 63;

    if (blk < SCORE_BLKS) {
        // ------------------------- score blocks -------------------------
        __shared__ float s2l[4][DR];
        const int gw = blk * 4 + wave;                // 0..8191
        const int t0 = gw * 2;                        // flat token = b*S+s
        const int batch = blk >> 9;                   // 512 blocks per batch
        const fx4* w4 = reinterpret_cast<const fx4*>(w);
        const fx4* h40 = reinterpret_cast<const fx4*>(hid) + (size_t)t0 * (H / 4);
        const fx4* h41 = h40 + (H / 4);

        float a00 = 0.f, a01 = 0.f, a02 = 0.f;        // token 0, depths 0..2
        float a10 = 0.f, a11 = 0.f, a12 = 0.f;        // token 1
#pragma unroll
        for (int j = 0; j < 8; ++j) {
            const int idx = j * 64 + lane;
            const fx4 hv0 = __builtin_nontemporal_load(h40 + idx);
            const fx4 hv1 = __builtin_nontemporal_load(h41 + idx);
            const fx4 w0 = w4[idx];
            const fx4 w1 = w4[idx + H / 4];
            const fx4 w2 = w4[idx + H / 2];
            a00 = fmaf(hv0.x, w0.x, a00); a10 = fmaf(hv1.x, w0.x, a10);
            a00 = fmaf(hv0.y, w0.y, a00); a10 = fmaf(hv1.y, w0.y, a10);
            a00 = fmaf(hv0.z, w0.z, a00); a10 = fmaf(hv1.z, w0.z, a10);
            a00 = fmaf(hv0.w, w0.w, a00); a10 = fmaf(hv1.w, w0.w, a10);
            a01 = fmaf(hv0.x, w1.x, a01); a11 = fmaf(hv1.x, w1.x, a11);
            a01 = fmaf(hv0.y, w1.y, a01); a11 = fmaf(hv1.y, w1.y, a11);
            a01 = fmaf(hv0.z, w1.z, a01); a11 = fmaf(hv1.z, w1.z, a11);
            a01 = fmaf(hv0.w, w1.w, a01); a11 = fmaf(hv1.w, w1.w, a11);
            a02 = fmaf(hv0.x, w2.x, a02); a12 = fmaf(hv1.x, w2.x, a12);
            a02 = fmaf(hv0.y, w2.y, a02); a12 = fmaf(hv1.y, w2.y, a12);
            a02 = fmaf(hv0.z, w2.z, a02); a12 = fmaf(hv1.z, w2.z, a12);
            a02 = fmaf(hv0.w, w2.w, a02); a12 = fmaf(hv1.w, w2.w, a12);
        }
#pragma unroll
        for (int off = 32; off >= 1; off >>= 1) {     // 64-lane butterfly x6
            a00 += __shfl_xor(a00, off); a01 += __shfl_xor(a01, off);
            a02 += __shfl_xor(a02, off); a10 += __shfl_xor(a10, off);
            a11 += __shfl_xor(a11, off); a12 += __shfl_xor(a12, off);
        }
        if (lane == 0) {
            const float s00 = 1.0f / (1.0f + expf(-a00));
            const float s01 = 1.0f / (1.0f + expf(-a01));
            const float s02 = 1.0f / (1.0f + expf(-a02));
            const float s10 = 1.0f / (1.0f + expf(-a10));
            const float s11 = 1.0f / (1.0f + expf(-a11));
            const float s12 = 1.0f / (1.0f + expf(-a12));
            uint2 kk;
            kk.x = __float_as_uint(s00);
            kk.y = __float_as_uint(s10);
            *reinterpret_cast<uint2*>(keys + t0) = kk;  // 8B aligned
            __threadfence();                            // make keys device-visible
            __hip_atomic_fetch_add(&cnt[batch], 1u, __ATOMIC_RELEASE,
                                   __HIP_MEMORY_SCOPE_AGENT);
            s2l[wave][0] = 1.0f / (1.0f + expf(-s00)) + 1.0f / (1.0f + expf(-s10));
            s2l[wave][1] = 1.0f / (1.0f + expf(-s01)) + 1.0f / (1.0f + expf(-s11));
            s2l[wave][2] = 1.0f / (1.0f + expf(-s02)) + 1.0f / (1.0f + expf(-s12));
        }
        __syncthreads();
        if (t == 0) {
            float p0 = 0.f, p1 = 0.f, p2 = 0.f;
#pragma unroll
            for (int v = 0; v < 4; ++v) { p0 += s2l[v][0]; p1 += s2l[v][1]; p2 += s2l[v][2]; }
            partials[0 * SCORE_BLKS + blk] = p0;        // plane-major per block
            partials[1 * SCORE_BLKS + blk] = p1;
            partials[2 * SCORE_BLKS + blk] = p2;
            __threadfence();
            __hip_atomic_fetch_add(&cnt[B], 1u, __ATOMIC_RELEASE,
                                   __HIP_MEMORY_SCOPE_AGENT);
        }
        return;
    }

    if (blk < SCORE_BLKS + B) {
        // ------------------------- select blocks -------------------------
        const int b = blk - SCORE_BLKS;
        __shared__ int wsum[2][4];
        __shared__ int wscan[4];
        if (t == 0) {
            while (__hip_atomic_load(&cnt[b], __ATOMIC_ACQUIRE,
                                     __HIP_MEMORY_SCOPE_AGENT) < (unsigned)WAVES_PER_BATCH)
                __builtin_amdgcn_s_sleep(8);
        }
        __syncthreads();

        // 16 consecutive keys per thread (index order preserved)
        const uint4* kp = reinterpret_cast<const uint4*>(keys + b * S + t * 16);
        const uint4 k0 = kp[0], k1 = kp[1], k2 = kp[2], k3 = kp[3];
        unsigned kr[16] = {k0.x, k0.y, k0.z, k0.w, k1.x, k1.y, k1.z, k1.w,
                           k2.x, k2.y, k2.z, k2.w, k3.x, k3.y, k3.z, k3.w};

        // fast path probe: count keys == 1.0f
        int c = 0;
#pragma unroll
        for (int i = 0; i < 16; ++i) c += (kr[i] == FONE);
#pragma unroll
        for (int off = 32; off >= 1; off >>= 1) c += __shfl_xor(c, off);
        if (lane == 0) wsum[0][wave] = c;
        __syncthreads();
        int tot1 = 0;
#pragma unroll
        for (int w2 = 0; w2 < 4; ++w2) tot1 += wsum[0][w2];

        unsigned vstar;
        int m;                                        // ties accepted (lowest index)
        if (tot1 >= KSEL) {                           // block-uniform decision
            vstar = FONE;
            m = KSEL;
        } else {
            unsigned v = 0;
            int pb = 1;
            for (int bit = 29; bit >= 0; --bit) {
                const unsigned cand = v | (1u << bit);
                int cc = 0;
#pragma unroll
                for (int i = 0; i < 16; ++i) cc += (kr[i] >= cand);
#pragma unroll
                for (int off = 32; off >= 1; off >>= 1) cc += __shfl_xor(cc, off);
                if (lane == 0) wsum[pb][wave] = cc;
                __syncthreads();
                int tot = 0;
#pragma unroll
                for (int w2 = 0; w2 < 4; ++w2) tot += wsum[pb][w2];
                if (tot >= KSEL) v = cand;
                pb ^= 1;
            }
            vstar = v;
            int cg = 0;
#pragma unroll
            for (int i = 0; i < 16; ++i) cg += (kr[i] > vstar);
#pragma unroll
            for (int off = 32; off >= 1; off >>= 1) cg += __shfl_xor(cg, off);
            if (lane == 0) wsum[pb][wave] = cg;
            __syncthreads();
            int g = 0;
#pragma unroll
            for (int w2 = 0; w2 < 4; ++w2) g += wsum[pb][w2];
            m = KSEL - g;
        }

        // stable tie rank via prefix scan of per-thread tie counts
        int tc = 0;
#pragma unroll
        for (int i = 0; i < 16; ++i) tc += (kr[i] == vstar);
        int sc = tc;                                  // inclusive wave scan
#pragma unroll
        for (int off = 1; off <= 32; off <<= 1) {
            const int o = __shfl_up(sc, off);
            if (lane >= off) sc += o;
        }
        if (lane == 63) wscan[wave] = sc;
        __syncthreads();
        int wbase = 0;
        for (int w2 = 0; w2 < wave; ++w2) wbase += wscan[w2];
        int rank = wbase + (sc - tc);

        // emit depth + masks
        float dep[16], f1[16];
#pragma unroll
        for (int i = 0; i < 16; ++i) {
            int sel;
            if (kr[i] > vstar) sel = 1;
            else if (kr[i] == vstar) { sel = (rank < m) ? 1 : 0; ++rank; }
            else sel = 0;
            dep[i] = sel ? 3.0f : 1.0f;
            f1[i] = sel ? 1.0f : 0.0f;
        }
        float* depth = out;                           // [B*S]
        float* masks = out + B * S + 1;               // [DR][B*S] (base misaligned)
        float4* dp4 = reinterpret_cast<float4*>(depth + b * S + t * 16);
#pragma unroll
        for (int q = 0; q < 4; ++q)
            dp4[q] = make_float4(dep[q * 4], dep[q * 4 + 1], dep[q * 4 + 2], dep[q * 4 + 3]);
        const int mb = b * S + t * 16;
#pragma unroll
        for (int i = 0; i < 16; ++i) {
            masks[0 * B * S + mb + i] = 1.0f;
            masks[1 * B * S + mb + i] = f1[i];
            masks[2 * B * S + mb + i] = f1[i];
        }
        return;
    }

    // --------------------------- loss block ---------------------------
    {
        __shared__ double red[3][4];
        if (t == 0) {
            while (__hip_atomic_load(&cnt[B], __ATOMIC_ACQUIRE,
                                     __HIP_MEMORY_SCOPE_AGENT) < (unsigned)SCORE_BLKS)
                __builtin_amdgcn_s_sleep(8);
        }
        __syncthreads();
        const float4* p4 = reinterpret_cast<const float4*>(partials);
        double a0 = 0.0, a1 = 0.0, a2 = 0.0;
        for (int i = t; i < SCORE_BLKS / 4; i += 256) {   // 512 float4 per plane
            const float4 v0 = p4[i];
            const float4 v1 = p4[SCORE_BLKS / 4 + i];
            const float4 v2 = p4[SCORE_BLKS / 2 + i];
            a0 += (double)v0.x + (double)v0.y + (double)v0.z + (double)v0.w;
            a1 += (double)v1.x + (double)v1.y + (double)v1.z + (double)v1.w;
            a2 += (double)v2.x + (double)v2.y + (double)v2.z + (double)v2.w;
        }
#pragma unroll
        for (int off = 32; off >= 1; off >>= 1) {
            a0 += __shfl_xor(a0, off);
            a1 += __shfl_xor(a1, off);
            a2 += __shfl_xor(a2, off);
        }
        if (lane == 0) { red[0][wave] = a0; red[1][wave] = a1; red[2][wave] = a2; }
        __syncthreads();
        if (t == 0) {
            double s0 = 0.0, s1 = 0.0, s2 = 0.0;
#pragma unroll
            for (int w2 = 0; w2 < 4; ++w2) { s0 += red[0][w2]; s1 += red[1][w2]; s2 += red[2][w2]; }
            const double n = (double)(B * S);
            const double lt = log(1.0 / 3.0);
            double l = (lt - log(s0 / n)) + (lt - log(s1 / n)) + (lt - log(s2 / n));
            out[B * S] = (float)(l * (1.0 / 3.0) / 3.0);
        }
    }
}

extern "C" void kernel_launch(void* const* d_in, const int* in_sizes, int n_in,
                              void* d_out, int out_size, void* d_ws, size_t ws_size,
                              hipStream_t stream) {
    const float* hid = (const float*)d_in[0];     // [B,S,H] f32
    const float* w   = (const float*)d_in[1];     // [DR,H] f32
    float* out = (float*)d_out;                   // depth[B*S] | loss | masks[DR*B*S]

    unsigned* keys  = (unsigned*)d_ws;                                    // 64 KiB
    float* partials = (float*)((char*)d_ws + 64 * 1024);                  // 24 KiB
    unsigned* cnt   = (unsigned*)((char*)d_ws + 96 * 1024);               // 5 uints

    hipMemsetAsync(cnt, 0, 32, stream);           // reset signals (graph-safe)
    ecr_fused<<<NBLK, 256, 0, stream>>>(hid, w, keys, partials, cnt, out);
}

// Round 7
// 40.884 us; speedup vs baseline: 17.0452x; 17.0452x over previous
//
#include <hip/hip_runtime.h>
#include <math.h>

namespace {
constexpr int B = 4;
constexpr int S = 4096;
constexpr int H = 2048;
constexpr int DR = 3;          // depth
constexpr int KSEL = 1365;     // int(4096/3)
constexpr int SCORE_BLKS = 2048;          // 4 waves/block, 2 tokens/wave
constexpr int NBLK = SCORE_BLKS + B + 1;  // + 4 select blocks + 1 loss block
constexpr unsigned FONE = 0x3F800000u;    // bits of 1.0f
constexpr unsigned SENTU = 0xFFFFFFFFu;   // memset-0xFF sentinel
constexpr unsigned long long SENT64 = 0xFFFFFFFFFFFFFFFFull;
}

// ---------------------------------------------------------------------------
// Fully fused, fence-free. Sync is pure data-flow:
//  - scratch (keys[B*S] ++ partials[3*SCORE_BLKS]) is memset to 0xFF per call;
//  - producers write key-pairs / partials via RELAXED agent-scope atomic
//    stores (coherent at LLC, no L2-writeback fences);
//  - the 5 consumer blocks (dispatched last -> no deadlock) spin with relaxed
//    agent-scope atomic loads until != sentinel. Each location transitions
//    sentinel -> final value exactly once, so no ordering is needed.
//  blocks [0,2048): scores. raw[d][t]=dot(hidden[t,:],w[d,:]); sc=sigmoid(raw)
//    (exp-form f32, matches XLA). keys = bits of sc0 (monotone on [0,1]).
//  blocks [2048,2052): per-batch exact top-KSEL (value desc, index asc),
//    fast path when count(key==1.0f) >= KSEL (saturated data).
//  block 2052: balancing-loss reduction.
// ---------------------------------------------------------------------------
__global__ __launch_bounds__(256) void ecr_fused(const float* __restrict__ hid,
                                                 const float* __restrict__ w,
                                                 unsigned* __restrict__ keys,
                                                 unsigned* __restrict__ partials,
                                                 float* __restrict__ out) {
    const int blk = blockIdx.x;
    const int t = threadIdx.x;
    const int wave = t >> 6;
    const int lane = t & 63;

    if (blk < SCORE_BLKS) {
        // ------------------------- score blocks -------------------------
        __shared__ float wl[DR * H];      // 24 KB staged weights
        __shared__ float s2l[4][DR];
        const float4* wg4 = reinterpret_cast<const float4*>(w);
        float4* wl4 = reinterpret_cast<float4*>(wl);
        for (int i = t; i < DR * H / 4; i += 256) wl4[i] = wg4[i];
        __syncthreads();

        const int gw = blk * 4 + wave;                // 0..8191
        const int t0 = gw * 2;                        // flat token = b*S+s
        const float4* wl4_0 = reinterpret_cast<const float4*>(wl);
        const float4* wl4_1 = wl4_0 + (H / 4);
        const float4* wl4_2 = wl4_0 + 2 * (H / 4);
        const float4* h40 = reinterpret_cast<const float4*>(hid) + (size_t)t0 * (H / 4);
        const float4* h41 = h40 + (H / 4);

        float a00 = 0.f, a01 = 0.f, a02 = 0.f;        // token 0, depths 0..2
        float a10 = 0.f, a11 = 0.f, a12 = 0.f;        // token 1
#pragma unroll
        for (int j = 0; j < 8; ++j) {                 // 2x float4 per lane/iter
            const int idx = j * 64 + lane;
            const float4 hv0 = h40[idx];
            const float4 hv1 = h41[idx];
            const float4 w0 = wl4_0[idx];
            const float4 w1 = wl4_1[idx];
            const float4 w2 = wl4_2[idx];
            a00 = fmaf(hv0.x, w0.x, a00); a10 = fmaf(hv1.x, w0.x, a10);
            a00 = fmaf(hv0.y, w0.y, a00); a10 = fmaf(hv1.y, w0.y, a10);
            a00 = fmaf(hv0.z, w0.z, a00); a10 = fmaf(hv1.z, w0.z, a10);
            a00 = fmaf(hv0.w, w0.w, a00); a10 = fmaf(hv1.w, w0.w, a10);
            a01 = fmaf(hv0.x, w1.x, a01); a11 = fmaf(hv1.x, w1.x, a11);
            a01 = fmaf(hv0.y, w1.y, a01); a11 = fmaf(hv1.y, w1.y, a11);
            a01 = fmaf(hv0.z, w1.z, a01); a11 = fmaf(hv1.z, w1.z, a11);
            a01 = fmaf(hv0.w, w1.w, a01); a11 = fmaf(hv1.w, w1.w, a11);
            a02 = fmaf(hv0.x, w2.x, a02); a12 = fmaf(hv1.x, w2.x, a12);
            a02 = fmaf(hv0.y, w2.y, a02); a12 = fmaf(hv1.y, w2.y, a12);
            a02 = fmaf(hv0.z, w2.z, a02); a12 = fmaf(hv1.z, w2.z, a12);
            a02 = fmaf(hv0.w, w2.w, a02); a12 = fmaf(hv1.w, w2.w, a12);
        }
#pragma unroll
        for (int off = 32; off >= 1; off >>= 1) {     // 64-lane butterfly x6
            a00 += __shfl_xor(a00, off); a01 += __shfl_xor(a01, off);
            a02 += __shfl_xor(a02, off); a10 += __shfl_xor(a10, off);
            a11 += __shfl_xor(a11, off); a12 += __shfl_xor(a12, off);
        }
        if (lane == 0) {
            const float s00 = 1.0f / (1.0f + expf(-a00));
            const float s01 = 1.0f / (1.0f + expf(-a01));
            const float s02 = 1.0f / (1.0f + expf(-a02));
            const float s10 = 1.0f / (1.0f + expf(-a10));
            const float s11 = 1.0f / (1.0f + expf(-a11));
            const float s12 = 1.0f / (1.0f + expf(-a12));
            const unsigned long long kk =
                (unsigned long long)__float_as_uint(s00) |
                ((unsigned long long)__float_as_uint(s10) << 32);
            __hip_atomic_store(reinterpret_cast<unsigned long long*>(keys + t0), kk,
                               __ATOMIC_RELAXED, __HIP_MEMORY_SCOPE_AGENT);
            s2l[wave][0] = 1.0f / (1.0f + expf(-s00)) + 1.0f / (1.0f + expf(-s10));
            s2l[wave][1] = 1.0f / (1.0f + expf(-s01)) + 1.0f / (1.0f + expf(-s11));
            s2l[wave][2] = 1.0f / (1.0f + expf(-s02)) + 1.0f / (1.0f + expf(-s12));
        }
        __syncthreads();
        if (t == 0) {
            float p0 = 0.f, p1 = 0.f, p2 = 0.f;
#pragma unroll
            for (int v = 0; v < 4; ++v) { p0 += s2l[v][0]; p1 += s2l[v][1]; p2 += s2l[v][2]; }
            __hip_atomic_store(&partials[0 * SCORE_BLKS + blk], __float_as_uint(p0),
                               __ATOMIC_RELAXED, __HIP_MEMORY_SCOPE_AGENT);
            __hip_atomic_store(&partials[1 * SCORE_BLKS + blk], __float_as_uint(p1),
                               __ATOMIC_RELAXED, __HIP_MEMORY_SCOPE_AGENT);
            __hip_atomic_store(&partials[2 * SCORE_BLKS + blk], __float_as_uint(p2),
                               __ATOMIC_RELAXED, __HIP_MEMORY_SCOPE_AGENT);
        }
        return;
    }

    if (blk < SCORE_BLKS + B) {
        // ------------------------- select blocks -------------------------
        const int b = blk - SCORE_BLKS;
        __shared__ int wsum[2][4];
        __shared__ int wscan[4];

        // spin-load 16 consecutive keys (8x 64-bit); single transition per loc
        unsigned kr[16];
        const unsigned long long* kp =
            reinterpret_cast<const unsigned long long*>(keys + b * S + t * 16);
#pragma unroll
        for (int q = 0; q < 8; ++q) {
            unsigned long long v;
            while ((v = __hip_atomic_load(&kp[q], __ATOMIC_RELAXED,
                                          __HIP_MEMORY_SCOPE_AGENT)) == SENT64)
                __builtin_amdgcn_s_sleep(1);
            kr[2 * q] = (unsigned)v;
            kr[2 * q + 1] = (unsigned)(v >> 32);
        }

        // fast path probe: count keys == 1.0f
        int c = 0;
#pragma unroll
        for (int i = 0; i < 16; ++i) c += (kr[i] == FONE);
#pragma unroll
        for (int off = 32; off >= 1; off >>= 1) c += __shfl_xor(c, off);
        if (lane == 0) wsum[0][wave] = c;
        __syncthreads();
        int tot1 = 0;
#pragma unroll
        for (int w2 = 0; w2 < 4; ++w2) tot1 += wsum[0][w2];

        unsigned vstar;
        int m;                                        // ties accepted (lowest index)
        if (tot1 >= KSEL) {                           // block-uniform decision
            vstar = FONE;
            m = KSEL;
        } else {
            unsigned v = 0;
            int pb = 1;
            for (int bit = 29; bit >= 0; --bit) {
                const unsigned cand = v | (1u << bit);
                int cc = 0;
#pragma unroll
                for (int i = 0; i < 16; ++i) cc += (kr[i] >= cand);
#pragma unroll
                for (int off = 32; off >= 1; off >>= 1) cc += __shfl_xor(cc, off);
                if (lane == 0) wsum[pb][wave] = cc;
                __syncthreads();
                int tot = 0;
#pragma unroll
                for (int w2 = 0; w2 < 4; ++w2) tot += wsum[pb][w2];
                if (tot >= KSEL) v = cand;
                pb ^= 1;
            }
            vstar = v;
            int cg = 0;
#pragma unroll
            for (int i = 0; i < 16; ++i) cg += (kr[i] > vstar);
#pragma unroll
            for (int off = 32; off >= 1; off >>= 1) cg += __shfl_xor(cg, off);
            if (lane == 0) wsum[pb][wave] = cg;
            __syncthreads();
            int g = 0;
#pragma unroll
            for (int w2 = 0; w2 < 4; ++w2) g += wsum[pb][w2];
            m = KSEL - g;
        }

        // stable tie rank via prefix scan of per-thread tie counts
        int tc = 0;
#pragma unroll
        for (int i = 0; i < 16; ++i) tc += (kr[i] == vstar);
        int sc = tc;                                  // inclusive wave scan
#pragma unroll
        for (int off = 1; off <= 32; off <<= 1) {
            const int o = __shfl_up(sc, off);
            if (lane >= off) sc += o;
        }
        if (lane == 63) wscan[wave] = sc;
        __syncthreads();
        int wbase = 0;
        for (int w2 = 0; w2 < wave; ++w2) wbase += wscan[w2];
        int rank = wbase + (sc - tc);

        // emit depth + masks
        float dep[16], f1[16];
#pragma unroll
        for (int i = 0; i < 16; ++i) {
            int sel;
            if (kr[i] > vstar) sel = 1;
            else if (kr[i] == vstar) { sel = (rank < m) ? 1 : 0; ++rank; }
            else sel = 0;
            dep[i] = sel ? 3.0f : 1.0f;
            f1[i] = sel ? 1.0f : 0.0f;
        }
        float* depth = out;                           // [B*S]
        float* masks = out + B * S + 1;               // [DR][B*S] (base misaligned)
        float4* dp4 = reinterpret_cast<float4*>(depth + b * S + t * 16);
#pragma unroll
        for (int q = 0; q < 4; ++q)
            dp4[q] = make_float4(dep[q * 4], dep[q * 4 + 1], dep[q * 4 + 2], dep[q * 4 + 3]);
        const int mb = b * S + t * 16;
#pragma unroll
        for (int i = 0; i < 16; ++i) {
            masks[0 * B * S + mb + i] = 1.0f;
            masks[1 * B * S + mb + i] = f1[i];
            masks[2 * B * S + mb + i] = f1[i];
        }
        return;
    }

    // --------------------------- loss block ---------------------------
    {
        __shared__ double red[3][4];
        double a0 = 0.0, a1 = 0.0, a2 = 0.0;
        for (int i = t; i < SCORE_BLKS; i += 256) {   // 8 per thread per plane
            unsigned u;
            while ((u = __hip_atomic_load(&partials[0 * SCORE_BLKS + i], __ATOMIC_RELAXED,
                                          __HIP_MEMORY_SCOPE_AGENT)) == SENTU)
                __builtin_amdgcn_s_sleep(1);
            a0 += (double)__uint_as_float(u);
        }
        for (int i = t; i < SCORE_BLKS; i += 256) {
            unsigned u;
            while ((u = __hip_atomic_load(&partials[1 * SCORE_BLKS + i], __ATOMIC_RELAXED,
                                          __HIP_MEMORY_SCOPE_AGENT)) == SENTU)
                __builtin_amdgcn_s_sleep(1);
            a1 += (double)__uint_as_float(u);
        }
        for (int i = t; i < SCORE_BLKS; i += 256) {
            unsigned u;
            while ((u = __hip_atomic_load(&partials[2 * SCORE_BLKS + i], __ATOMIC_RELAXED,
                                          __HIP_MEMORY_SCOPE_AGENT)) == SENTU)
                __builtin_amdgcn_s_sleep(1);
            a2 += (double)__uint_as_float(u);
        }
#pragma unroll
        for (int off = 32; off >= 1; off >>= 1) {
            a0 += __shfl_xor(a0, off);
            a1 += __shfl_xor(a1, off);
            a2 += __shfl_xor(a2, off);
        }
        if (lane == 0) { red[0][wave] = a0; red[1][wave] = a1; red[2][wave] = a2; }
        __syncthreads();
        if (t == 0) {
            double s0 = 0.0, s1 = 0.0, s2 = 0.0;
#pragma unroll
            for (int w2 = 0; w2 < 4; ++w2) { s0 += red[0][w2]; s1 += red[1][w2]; s2 += red[2][w2]; }
            const double n = (double)(B * S);
            const double lt = log(1.0 / 3.0);
            double l = (lt - log(s0 / n)) + (lt - log(s1 / n)) + (lt - log(s2 / n));
            out[B * S] = (float)(l * (1.0 / 3.0) / 3.0);
        }
    }
}

extern "C" void kernel_launch(void* const* d_in, const int* in_sizes, int n_in,
                              void* d_out, int out_size, void* d_ws, size_t ws_size,
                              hipStream_t stream) {
    const float* hid = (const float*)d_in[0];     // [B,S,H] f32
    const float* w   = (const float*)d_in[1];     // [DR,H] f32
    float* out = (float*)d_out;                   // depth[B*S] | loss | masks[DR*B*S]

    unsigned* keys     = (unsigned*)d_ws;                         // B*S uints (64 KiB)
    unsigned* partials = keys + B * S;                            // 3*SCORE_BLKS uints (24 KiB)

    // sentinel-fill the signaling scratch (keys ++ partials) each call
    hipMemsetAsync(d_ws, 0xFF, (size_t)(B * S + 3 * SCORE_BLKS) * sizeof(unsigned), stream);
    ecr_fused<<<NBLK, 256, 0, stream>>>(hid, w, keys, partials, out);
}

// Round 8
// 37.460 us; speedup vs baseline: 18.6032x; 1.0914x over previous
//
#include <hip/hip_runtime.h>
#include <math.h>

namespace {
constexpr int B = 4;
constexpr int S = 4096;
constexpr int H = 2048;
constexpr int DR = 3;          // depth
constexpr int KSEL = 1365;     // int(4096/3)
constexpr int NBLK1 = 1024;    // score blocks: 4 waves x 4 tokens
constexpr int NWAVE = NBLK1 * 4;          // 4096 waves
constexpr unsigned FONE = 0x3F800000u;    // bits of 1.0f
}

// ---------------------------------------------------------------------------
// K1: raw[d][t] = dot(hidden[t,:], w[d,:]); sc = sigmoid(raw) (exp-form f32,
//     matches XLA). 4 tokens per wave (12 indep. accumulator chains, 4 row
//     streams) for memory-level parallelism. No LDS, no barriers: weights
//     (24 KiB) via plain cached loads (L1-hot after first touch; L3 keeps
//     half of hidden resident across replays). Keys = bits of sc0, uint4
//     store. Loss partials plane-major per wave: partials[d*NWAVE + gw].
// ---------------------------------------------------------------------------
__global__ __launch_bounds__(256, 4) void ecr_scores(const float* __restrict__ hid,
                                                     const float* __restrict__ w,
                                                     unsigned* __restrict__ keys,
                                                     float* __restrict__ partials) {
    const int wave = threadIdx.x >> 6;
    const int lane = threadIdx.x & 63;
    const int gw = blockIdx.x * 4 + wave;             // 0..4095
    const int t0 = gw * 4;                            // flat token = b*S+s
    const float4* w4 = reinterpret_cast<const float4*>(w);
    const float4* h0 = reinterpret_cast<const float4*>(hid) + (size_t)t0 * (H / 4);
    const float4* h1 = h0 + (H / 4);
    const float4* h2 = h1 + (H / 4);
    const float4* h3 = h2 + (H / 4);

    float a00 = 0.f, a01 = 0.f, a02 = 0.f;            // token 0, depths 0..2
    float a10 = 0.f, a11 = 0.f, a12 = 0.f;
    float a20 = 0.f, a21 = 0.f, a22 = 0.f;
    float a30 = 0.f, a31 = 0.f, a32 = 0.f;
#pragma unroll
    for (int j = 0; j < 8; ++j) {
        const int idx = j * 64 + lane;
        const float4 hv0 = h0[idx];
        const float4 hv1 = h1[idx];
        const float4 hv2 = h2[idx];
        const float4 hv3 = h3[idx];
        const float4 w0 = w4[idx];                    // L1-hot rows
        const float4 w1 = w4[idx + H / 4];
        const float4 w2 = w4[idx + H / 2];
        a00 = fmaf(hv0.x, w0.x, a00); a10 = fmaf(hv1.x, w0.x, a10);
        a20 = fmaf(hv2.x, w0.x, a20); a30 = fmaf(hv3.x, w0.x, a30);
        a00 = fmaf(hv0.y, w0.y, a00); a10 = fmaf(hv1.y, w0.y, a10);
        a20 = fmaf(hv2.y, w0.y, a20); a30 = fmaf(hv3.y, w0.y, a30);
        a00 = fmaf(hv0.z, w0.z, a00); a10 = fmaf(hv1.z, w0.z, a10);
        a20 = fmaf(hv2.z, w0.z, a20); a30 = fmaf(hv3.z, w0.z, a30);
        a00 = fmaf(hv0.w, w0.w, a00); a10 = fmaf(hv1.w, w0.w, a10);
        a20 = fmaf(hv2.w, w0.w, a20); a30 = fmaf(hv3.w, w0.w, a30);
        a01 = fmaf(hv0.x, w1.x, a01); a11 = fmaf(hv1.x, w1.x, a11);
        a21 = fmaf(hv2.x, w1.x, a21); a31 = fmaf(hv3.x, w1.x, a31);
        a01 = fmaf(hv0.y, w1.y, a01); a11 = fmaf(hv1.y, w1.y, a11);
        a21 = fmaf(hv2.y, w1.y, a21); a31 = fmaf(hv3.y, w1.y, a31);
        a01 = fmaf(hv0.z, w1.z, a01); a11 = fmaf(hv1.z, w1.z, a11);
        a21 = fmaf(hv2.z, w1.z, a21); a31 = fmaf(hv3.z, w1.z, a31);
        a01 = fmaf(hv0.w, w1.w, a01); a11 = fmaf(hv1.w, w1.w, a11);
        a21 = fmaf(hv2.w, w1.w, a21); a31 = fmaf(hv3.w, w1.w, a31);
        a02 = fmaf(hv0.x, w2.x, a02); a12 = fmaf(hv1.x, w2.x, a12);
        a22 = fmaf(hv2.x, w2.x, a22); a32 = fmaf(hv3.x, w2.x, a32);
        a02 = fmaf(hv0.y, w2.y, a02); a12 = fmaf(hv1.y, w2.y, a12);
        a22 = fmaf(hv2.y, w2.y, a22); a32 = fmaf(hv3.y, w2.y, a32);
        a02 = fmaf(hv0.z, w2.z, a02); a12 = fmaf(hv1.z, w2.z, a12);
        a22 = fmaf(hv2.z, w2.z, a22); a32 = fmaf(hv3.z, w2.z, a32);
        a02 = fmaf(hv0.w, w2.w, a02); a12 = fmaf(hv1.w, w2.w, a12);
        a22 = fmaf(hv2.w, w2.w, a22); a32 = fmaf(hv3.w, w2.w, a32);
    }
#pragma unroll
    for (int off = 32; off >= 1; off >>= 1) {         // 64-lane butterfly x6
        a00 += __shfl_xor(a00, off); a01 += __shfl_xor(a01, off); a02 += __shfl_xor(a02, off);
        a10 += __shfl_xor(a10, off); a11 += __shfl_xor(a11, off); a12 += __shfl_xor(a12, off);
        a20 += __shfl_xor(a20, off); a21 += __shfl_xor(a21, off); a22 += __shfl_xor(a22, off);
        a30 += __shfl_xor(a30, off); a31 += __shfl_xor(a31, off); a32 += __shfl_xor(a32, off);
    }
    if (lane == 0) {
        const float s00 = 1.0f / (1.0f + expf(-a00));
        const float s10 = 1.0f / (1.0f + expf(-a10));
        const float s20 = 1.0f / (1.0f + expf(-a20));
        const float s30 = 1.0f / (1.0f + expf(-a30));
        const float s01 = 1.0f / (1.0f + expf(-a01));
        const float s11 = 1.0f / (1.0f + expf(-a11));
        const float s21 = 1.0f / (1.0f + expf(-a21));
        const float s31 = 1.0f / (1.0f + expf(-a31));
        const float s02 = 1.0f / (1.0f + expf(-a02));
        const float s12 = 1.0f / (1.0f + expf(-a12));
        const float s22 = 1.0f / (1.0f + expf(-a22));
        const float s32 = 1.0f / (1.0f + expf(-a32));
        uint4 kk;
        kk.x = __float_as_uint(s00);
        kk.y = __float_as_uint(s10);
        kk.z = __float_as_uint(s20);
        kk.w = __float_as_uint(s30);
        *reinterpret_cast<uint4*>(keys + t0) = kk;    // t0 % 4 == 0 -> 16B aligned
        partials[0 * NWAVE + gw] = 1.0f / (1.0f + expf(-s00)) + 1.0f / (1.0f + expf(-s10))
                                 + 1.0f / (1.0f + expf(-s20)) + 1.0f / (1.0f + expf(-s30));
        partials[1 * NWAVE + gw] = 1.0f / (1.0f + expf(-s01)) + 1.0f / (1.0f + expf(-s11))
                                 + 1.0f / (1.0f + expf(-s21)) + 1.0f / (1.0f + expf(-s31));
        partials[2 * NWAVE + gw] = 1.0f / (1.0f + expf(-s02)) + 1.0f / (1.0f + expf(-s12))
                                 + 1.0f / (1.0f + expf(-s22)) + 1.0f / (1.0f + expf(-s32));
    }
}

// ---------------------------------------------------------------------------
// K2: per-batch exact top-KSEL (value desc, index asc). Fast path: if
//     count(key == 1.0f) >= KSEL (saturated sigmoid data), v*=1.0f directly;
//     else branch-uniform bitwise binary search. Stable tie rank via shuffle
//     prefix scan. Block 0 fuses the balancing-loss reduction.
// ---------------------------------------------------------------------------
__global__ __launch_bounds__(512) void ecr_select(const unsigned* __restrict__ keys,
                                                  const float* __restrict__ partials,
                                                  float* __restrict__ out) {
    const int b = blockIdx.x;
    const int t = threadIdx.x;
    const int wave = t >> 6;
    const int lane = t & 63;

    __shared__ int wsum[2][8];
    __shared__ int wscan[8];

    // each thread holds 8 consecutive keys in registers (index order preserved)
    const uint4* kp = reinterpret_cast<const uint4*>(keys + b * S + t * 8);
    const uint4 ka = kp[0], kb = kp[1];
    unsigned kr[8] = {ka.x, ka.y, ka.z, ka.w, kb.x, kb.y, kb.z, kb.w};

    // ---- fast path probe: count keys == 1.0f ----
    int c = 0;
#pragma unroll
    for (int i = 0; i < 8; ++i) c += (kr[i] == FONE);
#pragma unroll
    for (int off = 32; off >= 1; off >>= 1) c += __shfl_xor(c, off);
    if (lane == 0) wsum[0][wave] = c;
    __syncthreads();
    int tot1 = 0;
#pragma unroll
    for (int w2 = 0; w2 < 8; ++w2) tot1 += wsum[0][w2];

    unsigned vstar;
    int m;                                            // ties accepted (lowest index)
    if (tot1 >= KSEL) {                               // block-uniform decision
        vstar = FONE;                                 // nothing can exceed 1.0f
        m = KSEL;
    } else {
        // ---- general bitwise binary search, 1 barrier per iteration ----
        unsigned v = 0;
        int pb = 1;
        for (int bit = 29; bit >= 0; --bit) {
            const unsigned cand = v | (1u << bit);
            int cc = 0;
#pragma unroll
            for (int i = 0; i < 8; ++i) cc += (kr[i] >= cand);
#pragma unroll
            for (int off = 32; off >= 1; off >>= 1) cc += __shfl_xor(cc, off);
            if (lane == 0) wsum[pb][wave] = cc;
            __syncthreads();
            int tot = 0;
#pragma unroll
            for (int w2 = 0; w2 < 8; ++w2) tot += wsum[pb][w2];
            if (tot >= KSEL) v = cand;
            pb ^= 1;
        }
        vstar = v;
        int cg = 0;
#pragma unroll
        for (int i = 0; i < 8; ++i) cg += (kr[i] > vstar);
#pragma unroll
        for (int off = 32; off >= 1; off >>= 1) cg += __shfl_xor(cg, off);
        if (lane == 0) wsum[pb][wave] = cg;
        __syncthreads();
        int g = 0;
#pragma unroll
        for (int w2 = 0; w2 < 8; ++w2) g += wsum[pb][w2];
        m = KSEL - g;
    }

    // ---- stable tie rank via prefix scan of per-thread tie counts ----
    int tc = 0;
#pragma unroll
    for (int i = 0; i < 8; ++i) tc += (kr[i] == vstar);
    int sc = tc;                                      // inclusive wave scan
#pragma unroll
    for (int off = 1; off <= 32; off <<= 1) {
        const int o = __shfl_up(sc, off);
        if (lane >= off) sc += o;
    }
    if (lane == 63) wscan[wave] = sc;                 // wave totals
    __syncthreads();
    int wbase = 0;
    for (int w2 = 0; w2 < wave; ++w2) wbase += wscan[w2];
    int rank = wbase + (sc - tc);                     // rank of this thread's first tie

    // ---- emit depth + masks ----
    float dep[8], f1[8];
#pragma unroll
    for (int i = 0; i < 8; ++i) {
        int sel;
        if (kr[i] > vstar) sel = 1;
        else if (kr[i] == vstar) { sel = (rank < m) ? 1 : 0; ++rank; }
        else sel = 0;
        dep[i] = sel ? 3.0f : 1.0f;
        f1[i] = sel ? 1.0f : 0.0f;
    }
    float* depth = out;                               // [B*S]
    float* masks = out + B * S + 1;                   // [DR][B*S] (base misaligned)
    float4* dp4 = reinterpret_cast<float4*>(depth + b * S + t * 8);
    dp4[0] = make_float4(dep[0], dep[1], dep[2], dep[3]);
    dp4[1] = make_float4(dep[4], dep[5], dep[6], dep[7]);
    const int mb = b * S + t * 8;
#pragma unroll
    for (int i = 0; i < 8; ++i) {
        masks[0 * B * S + mb + i] = 1.0f;
        masks[1 * B * S + mb + i] = f1[i];
        masks[2 * B * S + mb + i] = f1[i];
    }

    // ---- block 0: fused balancing-loss reduction (plane-major partials) ----
    if (b == 0) {
        __shared__ double red[3][8];
        const float4* p4 = reinterpret_cast<const float4*>(partials);
        double a0 = 0.0, a1 = 0.0, a2 = 0.0;
        for (int i = t; i < NWAVE / 4; i += 512) {    // 1024 float4 per plane
            const float4 v0 = p4[i];
            const float4 v1 = p4[NWAVE / 4 + i];
            const float4 v2 = p4[NWAVE / 2 + i];
            a0 += (double)v0.x + (double)v0.y + (double)v0.z + (double)v0.w;
            a1 += (double)v1.x + (double)v1.y + (double)v1.z + (double)v1.w;
            a2 += (double)v2.x + (double)v2.y + (double)v2.z + (double)v2.w;
        }
#pragma unroll
        for (int off = 32; off >= 1; off >>= 1) {
            a0 += __shfl_xor(a0, off);
            a1 += __shfl_xor(a1, off);
            a2 += __shfl_xor(a2, off);
        }
        if (lane == 0) { red[0][wave] = a0; red[1][wave] = a1; red[2][wave] = a2; }
        __syncthreads();
        if (t == 0) {
            double s0 = 0.0, s1 = 0.0, s2 = 0.0;
#pragma unroll
            for (int w2 = 0; w2 < 8; ++w2) { s0 += red[0][w2]; s1 += red[1][w2]; s2 += red[2][w2]; }
            const double n = (double)(B * S);
            const double lt = log(1.0 / 3.0);
            double l = (lt - log(s0 / n)) + (lt - log(s1 / n)) + (lt - log(s2 / n));
            out[B * S] = (float)(l * (1.0 / 3.0) / 3.0);
        }
    }
}

extern "C" void kernel_launch(void* const* d_in, const int* in_sizes, int n_in,
                              void* d_out, int out_size, void* d_ws, size_t ws_size,
                              hipStream_t stream) {
    const float* hid = (const float*)d_in[0];     // [B,S,H] f32
    const float* w   = (const float*)d_in[1];     // [DR,H] f32
    float* out = (float*)d_out;                   // depth[B*S] | loss | masks[DR*B*S]

    unsigned* keys  = (unsigned*)d_ws;                                   // B*S uints (64 KiB)
    float* partials = (float*)((char*)d_ws + (size_t)B * S * sizeof(unsigned)); // 3*NWAVE f32 (48 KiB)

    ecr_scores<<<NBLK1, 256, 0, stream>>>(hid, w, keys, partials);
    ecr_select<<<B, 512, 0, stream>>>(keys, partials, out);
}

// Round 9
// 37.013 us; speedup vs baseline: 18.8278x; 1.0121x over previous
//
#include <hip/hip_runtime.h>
#include <math.h>

namespace {
constexpr int B = 4;
constexpr int S = 4096;
constexpr int H = 2048;
constexpr int DR = 3;          // depth
constexpr int KSEL = 1365;     // int(4096/3)
constexpr int NBLK1 = 2048;    // score blocks: 4 waves x 2 tokens
constexpr unsigned FONE = 0x3F800000u;    // bits of 1.0f
}

// ---------------------------------------------------------------------------
// K1: raw[d][t] = dot(hidden[t,:], w[d,:]); sc = sigmoid(raw) (exp-form f32,
//     matches XLA). LDS-staged weights, 2 tokens/wave interleaved (best
//     measured variant). Also fills masks[0] (all-ones plane) so the select
//     kernel doesn't have to. Loss partials plane-major per block.
// ---------------------------------------------------------------------------
__global__ __launch_bounds__(256) void ecr_scores(const float* __restrict__ hid,
                                                  const float* __restrict__ w,
                                                  unsigned* __restrict__ keys,
                                                  float* __restrict__ partials,
                                                  float* __restrict__ out) {
    __shared__ float wl[DR * H];        // 24 KB staged weights
    __shared__ float s2l[4][DR];
    const float4* wg4 = reinterpret_cast<const float4*>(w);
    float4* wl4 = reinterpret_cast<float4*>(wl);
    for (int i = threadIdx.x; i < DR * H / 4; i += 256) wl4[i] = wg4[i];
    __syncthreads();

    const int wave = threadIdx.x >> 6;
    const int lane = threadIdx.x & 63;
    const int gw = blockIdx.x * 4 + wave;             // 0..8191
    const int t0 = gw * 2;                            // flat token = b*S+s
    const float4* wl4_0 = reinterpret_cast<const float4*>(wl);
    const float4* wl4_1 = wl4_0 + (H / 4);
    const float4* wl4_2 = wl4_0 + 2 * (H / 4);
    const float4* h40 = reinterpret_cast<const float4*>(hid) + (size_t)t0 * (H / 4);
    const float4* h41 = h40 + (H / 4);

    float a00 = 0.f, a01 = 0.f, a02 = 0.f;            // token 0, depths 0..2
    float a10 = 0.f, a11 = 0.f, a12 = 0.f;            // token 1
#pragma unroll
    for (int j = 0; j < 8; ++j) {                     // 2x float4 per lane/iter
        const int idx = j * 64 + lane;
        const float4 hv0 = h40[idx];
        const float4 hv1 = h41[idx];
        const float4 w0 = wl4_0[idx];
        const float4 w1 = wl4_1[idx];
        const float4 w2 = wl4_2[idx];
        a00 = fmaf(hv0.x, w0.x, a00); a10 = fmaf(hv1.x, w0.x, a10);
        a00 = fmaf(hv0.y, w0.y, a00); a10 = fmaf(hv1.y, w0.y, a10);
        a00 = fmaf(hv0.z, w0.z, a00); a10 = fmaf(hv1.z, w0.z, a10);
        a00 = fmaf(hv0.w, w0.w, a00); a10 = fmaf(hv1.w, w0.w, a10);
        a01 = fmaf(hv0.x, w1.x, a01); a11 = fmaf(hv1.x, w1.x, a11);
        a01 = fmaf(hv0.y, w1.y, a01); a11 = fmaf(hv1.y, w1.y, a11);
        a01 = fmaf(hv0.z, w1.z, a01); a11 = fmaf(hv1.z, w1.z, a11);
        a01 = fmaf(hv0.w, w1.w, a01); a11 = fmaf(hv1.w, w1.w, a11);
        a02 = fmaf(hv0.x, w2.x, a02); a12 = fmaf(hv1.x, w2.x, a12);
        a02 = fmaf(hv0.y, w2.y, a02); a12 = fmaf(hv1.y, w2.y, a12);
        a02 = fmaf(hv0.z, w2.z, a02); a12 = fmaf(hv1.z, w2.z, a12);
        a02 = fmaf(hv0.w, w2.w, a02); a12 = fmaf(hv1.w, w2.w, a12);
    }
#pragma unroll
    for (int off = 32; off >= 1; off >>= 1) {         // 64-lane butterfly x6
        a00 += __shfl_xor(a00, off); a01 += __shfl_xor(a01, off);
        a02 += __shfl_xor(a02, off); a10 += __shfl_xor(a10, off);
        a11 += __shfl_xor(a11, off); a12 += __shfl_xor(a12, off);
    }
    if (lane == 0) {
        const float s00 = 1.0f / (1.0f + expf(-a00));
        const float s01 = 1.0f / (1.0f + expf(-a01));
        const float s02 = 1.0f / (1.0f + expf(-a02));
        const float s10 = 1.0f / (1.0f + expf(-a10));
        const float s11 = 1.0f / (1.0f + expf(-a11));
        const float s12 = 1.0f / (1.0f + expf(-a12));
        uint2 kk;
        kk.x = __float_as_uint(s00);
        kk.y = __float_as_uint(s10);
        *reinterpret_cast<uint2*>(keys + t0) = kk;    // t0 even -> 8B aligned
        s2l[wave][0] = 1.0f / (1.0f + expf(-s00)) + 1.0f / (1.0f + expf(-s10));
        s2l[wave][1] = 1.0f / (1.0f + expf(-s01)) + 1.0f / (1.0f + expf(-s11));
        s2l[wave][2] = 1.0f / (1.0f + expf(-s02)) + 1.0f / (1.0f + expf(-s12));
    }
    __syncthreads();
    if (threadIdx.x == 0) {
        float p0 = 0.f, p1 = 0.f, p2 = 0.f;
#pragma unroll
        for (int v = 0; v < 4; ++v) { p0 += s2l[v][0]; p1 += s2l[v][1]; p2 += s2l[v][2]; }
        partials[0 * NBLK1 + blockIdx.x] = p0;        // plane-major per block
        partials[1 * NBLK1 + blockIdx.x] = p1;
        partials[2 * NBLK1 + blockIdx.x] = p2;
    }
    // masks[0] plane (all ones): 8 consecutive floats per block, coalesced.
    if (threadIdx.x < 8)
        out[B * S + 1 + blockIdx.x * 8 + threadIdx.x] = 1.0f;
}

// ---------------------------------------------------------------------------
// K2: per-batch exact top-KSEL (value desc, index asc), STRIDED ownership:
//     thread t owns keys {t, t+512, ..., t+3584} so every key load and every
//     depth/mask store is lane-consecutive (fully coalesced). Counting is
//     order-independent; stable tie rank = 8 per-level block prefix scans
//     (global index i*512+t is lex in (i,t)). Fast path when
//     count(key==1.0f) >= KSEL. Block 0 fuses the balancing-loss reduction.
// ---------------------------------------------------------------------------
__global__ __launch_bounds__(512) void ecr_select(const unsigned* __restrict__ keys,
                                                  const float* __restrict__ partials,
                                                  float* __restrict__ out) {
    const int b = blockIdx.x;
    const int t = threadIdx.x;
    const int wave = t >> 6;
    const int lane = t & 63;

    __shared__ int wsum[2][8];
    __shared__ int wscan[8];

    // 8 strided keys per thread: global index of kr[i] is i*512 + t
    unsigned kr[8];
#pragma unroll
    for (int i = 0; i < 8; ++i) kr[i] = keys[b * S + i * 512 + t];

    // ---- fast path probe: count keys == 1.0f ----
    int c = 0;
#pragma unroll
    for (int i = 0; i < 8; ++i) c += (kr[i] == FONE);
#pragma unroll
    for (int off = 32; off >= 1; off >>= 1) c += __shfl_xor(c, off);
    if (lane == 0) wsum[0][wave] = c;
    __syncthreads();
    int tot1 = 0;
#pragma unroll
    for (int w2 = 0; w2 < 8; ++w2) tot1 += wsum[0][w2];

    unsigned vstar;
    int m;                                            // ties accepted (lowest index)
    if (tot1 >= KSEL) {                               // block-uniform decision
        vstar = FONE;                                 // nothing can exceed 1.0f
        m = KSEL;
    } else {
        // ---- general bitwise binary search, 1 barrier per iteration ----
        unsigned v = 0;
        int pb = 1;
        for (int bit = 29; bit >= 0; --bit) {
            const unsigned cand = v | (1u << bit);
            int cc = 0;
#pragma unroll
            for (int i = 0; i < 8; ++i) cc += (kr[i] >= cand);
#pragma unroll
            for (int off = 32; off >= 1; off >>= 1) cc += __shfl_xor(cc, off);
            if (lane == 0) wsum[pb][wave] = cc;
            __syncthreads();
            int tot = 0;
#pragma unroll
            for (int w2 = 0; w2 < 8; ++w2) tot += wsum[pb][w2];
            if (tot >= KSEL) v = cand;
            pb ^= 1;
        }
        vstar = v;
        int cg = 0;
#pragma unroll
        for (int i = 0; i < 8; ++i) cg += (kr[i] > vstar);
#pragma unroll
        for (int off = 32; off >= 1; off >>= 1) cg += __shfl_xor(cg, off);
        if (lane == 0) wsum[pb][wave] = cg;
        __syncthreads();
        int g = 0;
#pragma unroll
        for (int w2 = 0; w2 < 8; ++w2) g += wsum[pb][w2];
        m = KSEL - g;
    }
    __syncthreads();

    // ---- stable tie ranks, level by level (global index = i*512 + t) ----
    int rank[8];
    int cum = 0;                                      // ties in levels < i
    for (int i = 0; i < 8; ++i) {
        const int tci = (kr[i] == vstar) ? 1 : 0;
        int sc = tci;                                 // inclusive wave scan
#pragma unroll
        for (int off = 1; off <= 32; off <<= 1) {
            const int o = __shfl_up(sc, off);
            if (lane >= off) sc += o;
        }
        if (lane == 63) wscan[wave] = sc;
        __syncthreads();
        int base = 0, tot = 0;
#pragma unroll
        for (int w2 = 0; w2 < 8; ++w2) {
            if (w2 < wave) base += wscan[w2];
            tot += wscan[w2];
        }
        rank[i] = cum + base + (sc - tci);            // ties with smaller index
        cum += tot;
        __syncthreads();                              // before wscan reuse
    }

    // ---- emit depth + masks[1,2], all lane-consecutive (coalesced) ----
    float* depth  = out;                              // [B*S]
    float* masks1 = out + B * S + 1 + 1 * B * S;      // [B*S]
    float* masks2 = out + B * S + 1 + 2 * B * S;      // [B*S]
    const int s0 = b * S + t;
#pragma unroll
    for (int i = 0; i < 8; ++i) {
        int sel;
        if (kr[i] > vstar) sel = 1;
        else if (kr[i] == vstar) sel = (rank[i] < m) ? 1 : 0;
        else sel = 0;
        const float fsel = sel ? 1.0f : 0.0f;
        depth[s0 + i * 512]  = sel ? 3.0f : 1.0f;
        masks1[s0 + i * 512] = fsel;
        masks2[s0 + i * 512] = fsel;
    }

    // ---- block 0: fused balancing-loss reduction (plane-major partials) ----
    if (b == 0) {
        __shared__ double red[3][8];
        const float4* p4 = reinterpret_cast<const float4*>(partials);
        // 2048 floats per plane = 512 float4 -> exactly one per thread
        const float4 v0 = p4[t];
        const float4 v1 = p4[NBLK1 / 4 + t];
        const float4 v2 = p4[NBLK1 / 2 + t];
        double a0 = (double)v0.x + (double)v0.y + (double)v0.z + (double)v0.w;
        double a1 = (double)v1.x + (double)v1.y + (double)v1.z + (double)v1.w;
        double a2 = (double)v2.x + (double)v2.y + (double)v2.z + (double)v2.w;
#pragma unroll
        for (int off = 32; off >= 1; off >>= 1) {
            a0 += __shfl_xor(a0, off);
            a1 += __shfl_xor(a1, off);
            a2 += __shfl_xor(a2, off);
        }
        if (lane == 0) { red[0][wave] = a0; red[1][wave] = a1; red[2][wave] = a2; }
        __syncthreads();
        if (t == 0) {
            double s0d = 0.0, s1d = 0.0, s2d = 0.0;
#pragma unroll
            for (int w2 = 0; w2 < 8; ++w2) { s0d += red[0][w2]; s1d += red[1][w2]; s2d += red[2][w2]; }
            const double n = (double)(B * S);
            const double lt = log(1.0 / 3.0);
            double l = (lt - log(s0d / n)) + (lt - log(s1d / n)) + (lt - log(s2d / n));
            out[B * S] = (float)(l * (1.0 / 3.0) / 3.0);
        }
    }
}

extern "C" void kernel_launch(void* const* d_in, const int* in_sizes, int n_in,
                              void* d_out, int out_size, void* d_ws, size_t ws_size,
                              hipStream_t stream) {
    const float* hid = (const float*)d_in[0];     // [B,S,H] f32
    const float* w   = (const float*)d_in[1];     // [DR,H] f32
    float* out = (float*)d_out;                   // depth[B*S] | loss | masks[DR*B*S]

    unsigned* keys  = (unsigned*)d_ws;                                   // B*S uints (64 KiB)
    float* partials = (float*)((char*)d_ws + (size_t)B * S * sizeof(unsigned)); // 3*NBLK1 f32 (24 KiB)

    ecr_scores<<<NBLK1, 256, 0, stream>>>(hid, w, keys, partials, out);
    ecr_select<<<B, 512, 0, stream>>>(keys, partials, out);
}